// Round 1
// baseline (1020.986 us; speedup 1.0000x reference)
//
#include <hip/hip_runtime.h>
#include <hip/hip_bf16.h>
#include <stdint.h>

#define TPB 512
#define R_ 64
#define MX_ 32
#define MY_ 24
#define NPIX 768

// LDS layout (byte offsets), phases reuse regions:
//  scatter : x0f f32[26*768]            @0      (79872)
//            x0h bf16[26][32][28]       @79872  (46592)  end 126464
//  conv0   : reads x0h, writes x1h bf16[32][32][26] @0      (53248)
//  conv1   : reads x1h, writes x2h bf16[64][32][26] @53248  (106496) end 159744
//  conv2   : reads x2h, writes x3h bf16[32][768]    @0      (49152)  (2 oc-halves)
//  MLP     : Ya f32[64*64] @0 (16384), Yb f32[64*64] @16384 (16384)

__device__ __forceinline__ float bl16(uint32_t u) { return __uint_as_float(u << 16); }
__device__ __forceinline__ float bh16(uint32_t u) { return __uint_as_float(u & 0xffff0000u); }

__global__ __launch_bounds__(TPB)
void fused_mainnet(const int* __restrict__ rpos,
                   const float* __restrict__ rooms,
                   const float* __restrict__ emb,
                   const float* __restrict__ w0, const float* __restrict__ b0,
                   const float* __restrict__ w1, const float* __restrict__ b1,
                   const float* __restrict__ w2, const float* __restrict__ b2,
                   const float* __restrict__ rw0, const float* __restrict__ rb0,
                   const float* __restrict__ rw1, const float* __restrict__ rb1,
                   const float* __restrict__ rw2, const float* __restrict__ rb2,
                   float* __restrict__ out)
{
    __shared__ __align__(16) unsigned char smem[159744];
    float*          x0f = (float*)smem;                              // [26][768]
    __hip_bfloat16* x0h = (__hip_bfloat16*)(smem + 79872);           // [26][32][28]
    __hip_bfloat16* x1h = (__hip_bfloat16*)(smem);                   // [32][32][26]
    __hip_bfloat16* x2h = (__hip_bfloat16*)(smem + 53248);           // [64][32][26]
    __hip_bfloat16* x3h = (__hip_bfloat16*)(smem);                   // [32][768]
    float*          Ya  = (float*)(smem);                            // [64][64]
    float*          Yb  = (float*)(smem + 16384);                    // [64][64]

    const int n   = blockIdx.x;
    const int tid = threadIdx.x;
    const int* rp = rpos + n * R_ * 2;

    // ---------------- build X0 (f32, LDS) ----------------
    for (int i = tid; i < 26 * NPIX; i += TPB)
        x0f[i] = (i >= 9 * NPIX && i < 10 * NPIX) ? 1.0f : 0.0f;   // bg channel = 1
    __syncthreads();

    for (int q = tid; q < R_ * 36; q += TPB) {
        const int r = q / 36, cell = q % 36;
        const float m = rooms[r * 9 * 36 + cell];
        if (m == 0.0f) continue;                 // all channels are 0 where mask==0
        const int i = cell / 6, j = cell % 6;
        const int pix = (rp[r * 2] + i) * MY_ + (rp[r * 2 + 1] + j);
        #pragma unroll
        for (int c = 0; c < 9; ++c) {
            const float v = rooms[(r * 9 + c) * 36 + cell];
            if (v != 0.0f) atomicAdd(&x0f[c * NPIX + pix], v);
        }
        const float* er = emb + r * 16;
        #pragma unroll
        for (int e = 0; e < 16; ++e)
            atomicAdd(&x0f[(10 + e) * NPIX + pix], er[e] * m);
    }
    __syncthreads();

    // convert to y-padded bf16 [26][32][28] (pad 2 each side in y)
    for (int q = tid; q < 26 * 32 * 28; q += TPB) {
        const int yy = q % 28, xx = (q / 28) % 32, ic = q / (28 * 32);
        float v = 0.0f;
        if (yy >= 2 && yy < 26) v = x0f[ic * NPIX + xx * MY_ + (yy - 2)];
        x0h[q] = __float2bfloat16(v);
    }
    __syncthreads();

    // ---------------- conv0: 26 -> 32, 5x5 ----------------
    for (int tile = tid; tile < 1536; tile += TPB) {          // 16 oc-pairs x 32 x x 3 y-tiles
        const int t = tile % 3, xx = (tile / 3) % 32, g = tile / 96;
        const int oc0 = g * 2, y0 = t * 8;
        float acc0[8], acc1[8];
        {
            const float bb0 = b0[oc0], bb1 = b0[oc0 + 1];
            #pragma unroll
            for (int y = 0; y < 8; ++y) { acc0[y] = bb0; acc1[y] = bb1; }
        }
        for (int ic = 0; ic < 26; ++ic) {
            #pragma unroll
            for (int dx = 0; dx < 5; ++dx) {
                const int xi = xx + dx - 2;
                if (xi < 0 || xi >= 32) continue;
                const uint32_t* rowp = (const uint32_t*)(x0h + (ic * 32 + xi) * 28 + y0);
                const uint32_t d0 = rowp[0], d1 = rowp[1], d2 = rowp[2],
                               d3 = rowp[3], d4 = rowp[4], d5 = rowp[5];
                const float in[12] = { bl16(d0), bh16(d0), bl16(d1), bh16(d1),
                                       bl16(d2), bh16(d2), bl16(d3), bh16(d3),
                                       bl16(d4), bh16(d4), bl16(d5), bh16(d5) };
                const float* wpa = w0 + oc0 * 650 + ic * 25 + dx * 5;
                const float* wpb = wpa + 650;
                #pragma unroll
                for (int dy = 0; dy < 5; ++dy) {
                    const float wa = wpa[dy], wb = wpb[dy];
                    #pragma unroll
                    for (int y = 0; y < 8; ++y) {
                        acc0[y] = fmaf(in[y + dy], wa, acc0[y]);
                        acc1[y] = fmaf(in[y + dy], wb, acc1[y]);
                    }
                }
            }
        }
        #pragma unroll
        for (int y = 0; y < 8; ++y) {
            x1h[(oc0 * 32 + xx) * 26 + y0 + y + 1]       = __float2bfloat16(fmaxf(acc0[y], 0.0f));
            x1h[((oc0 + 1) * 32 + xx) * 26 + y0 + y + 1] = __float2bfloat16(fmaxf(acc1[y], 0.0f));
        }
    }
    for (int q = tid; q < 32 * 32; q += TPB) {               // y-pads
        x1h[q * 26]      = __float2bfloat16(0.0f);
        x1h[q * 26 + 25] = __float2bfloat16(0.0f);
    }
    __syncthreads();

    // ---------------- conv1: 32 -> 64, 3x3 ----------------
    for (int tile = tid; tile < 1536; tile += TPB) {          // 16 oc-quads x 32 x 3
        const int t = tile % 3, xx = (tile / 3) % 32, g = tile / 96;
        const int oc0 = g * 4, y0 = t * 8;
        float acc[4][8];
        #pragma unroll
        for (int o = 0; o < 4; ++o) {
            const float bb = b1[oc0 + o];
            #pragma unroll
            for (int y = 0; y < 8; ++y) acc[o][y] = bb;
        }
        for (int ic = 0; ic < 32; ++ic) {
            #pragma unroll
            for (int dx = 0; dx < 3; ++dx) {
                const int xi = xx + dx - 1;
                if (xi < 0 || xi >= 32) continue;
                const uint32_t* rowp = (const uint32_t*)(x1h + (ic * 32 + xi) * 26 + y0);
                const uint32_t d0 = rowp[0], d1 = rowp[1], d2 = rowp[2],
                               d3 = rowp[3], d4 = rowp[4];
                const float in[10] = { bl16(d0), bh16(d0), bl16(d1), bh16(d1),
                                       bl16(d2), bh16(d2), bl16(d3), bh16(d3),
                                       bl16(d4), bh16(d4) };
                #pragma unroll
                for (int o = 0; o < 4; ++o) {
                    const float* wp = w1 + (oc0 + o) * 288 + ic * 9 + dx * 3;
                    const float wv0 = wp[0], wv1 = wp[1], wv2 = wp[2];
                    #pragma unroll
                    for (int y = 0; y < 8; ++y)
                        acc[o][y] = fmaf(in[y], wv0, fmaf(in[y + 1], wv1, fmaf(in[y + 2], wv2, acc[o][y])));
                }
            }
        }
        #pragma unroll
        for (int o = 0; o < 4; ++o)
            #pragma unroll
            for (int y = 0; y < 8; ++y)
                x2h[((oc0 + o) * 32 + xx) * 26 + y0 + y + 1] = __float2bfloat16(fmaxf(acc[o][y], 0.0f));
    }
    for (int q = tid; q < 64 * 32; q += TPB) {               // y-pads
        x2h[q * 26]      = __float2bfloat16(0.0f);
        x2h[q * 26 + 25] = __float2bfloat16(0.0f);
    }
    __syncthreads();

    // ---------------- conv2 (64->64, 3x3) in two 32-oc halves + fused gather ----------------
    float yreg[8];
    #pragma unroll
    for (int h = 0; h < 2; ++h) {
        for (int tile = tid; tile < 1536; tile += TPB) {      // 16 oc-pairs x 32 x 3
            const int t = tile % 3, xx = (tile / 3) % 32, g = tile / 96;
            const int op0 = g * 2, y0 = t * 8;
            float acc0[8], acc1[8];
            {
                const float bb0 = b2[h * 32 + op0], bb1 = b2[h * 32 + op0 + 1];
                #pragma unroll
                for (int y = 0; y < 8; ++y) { acc0[y] = bb0; acc1[y] = bb1; }
            }
            for (int ic = 0; ic < 64; ++ic) {
                #pragma unroll
                for (int dx = 0; dx < 3; ++dx) {
                    const int xi = xx + dx - 1;
                    if (xi < 0 || xi >= 32) continue;
                    const uint32_t* rowp = (const uint32_t*)(x2h + (ic * 32 + xi) * 26 + y0);
                    const uint32_t d0 = rowp[0], d1 = rowp[1], d2 = rowp[2],
                                   d3 = rowp[3], d4 = rowp[4];
                    const float in[10] = { bl16(d0), bh16(d0), bl16(d1), bh16(d1),
                                           bl16(d2), bh16(d2), bl16(d3), bh16(d3),
                                           bl16(d4), bh16(d4) };
                    const float* wpa = w2 + (h * 32 + op0) * 576 + ic * 9 + dx * 3;
                    const float* wpb = wpa + 576;
                    const float a0 = wpa[0], a1 = wpa[1], a2 = wpa[2];
                    const float c0 = wpb[0], c1 = wpb[1], c2 = wpb[2];
                    #pragma unroll
                    for (int y = 0; y < 8; ++y) {
                        acc0[y] = fmaf(in[y], a0, fmaf(in[y + 1], a1, fmaf(in[y + 2], a2, acc0[y])));
                        acc1[y] = fmaf(in[y], c0, fmaf(in[y + 1], c1, fmaf(in[y + 2], c2, acc1[y])));
                    }
                }
            }
            #pragma unroll
            for (int y = 0; y < 8; ++y) {
                x3h[op0 * NPIX + xx * MY_ + y0 + y]       = __float2bfloat16(fmaxf(acc0[y], 0.0f));
                x3h[(op0 + 1) * NPIX + xx * MY_ + y0 + y] = __float2bfloat16(fmaxf(acc1[y], 0.0f));
            }
        }
        __syncthreads();
        // gather this half: Y[oc][r] = sum_cells mask * X3   -> registers
        #pragma unroll
        for (int k = 0; k < 4; ++k) {
            const int q = tid + TPB * k;                      // 2048 (oc',r) pairs
            const int op = q >> 6, r = q & 63;
            const int px = rp[r * 2], py = rp[r * 2 + 1];
            const float* mrow = rooms + r * 9 * 36;
            float s = 0.0f;
            #pragma unroll
            for (int i = 0; i < 6; ++i)
                #pragma unroll
                for (int j = 0; j < 6; ++j) {
                    const float m = mrow[i * 6 + j];
                    s += m * __bfloat162float(x3h[op * NPIX + (px + i) * MY_ + (py + j)]);
                }
            yreg[h * 4 + k] = s;
        }
        __syncthreads();
    }

    // assemble Y into LDS
    #pragma unroll
    for (int k = 0; k < 8; ++k) {
        const int q = tid + TPB * (k & 3);
        const int op = q >> 6, r = q & 63;
        Ya[((k >> 2) * 32 + op) * 64 + r] = yreg[k];
    }
    __syncthreads();

    // ---------------- room MLP: 3x (64x64) ----------------
    // L0: Ya -> Yb, relu
    #pragma unroll
    for (int k = 0; k < 8; ++k) {
        const int q = tid + TPB * k;
        const int o = q >> 6, r = q & 63;
        float acc = rb0[o];
        const float* wp = rw0 + o * 64;
        #pragma unroll 8
        for (int c = 0; c < 64; ++c) acc = fmaf(wp[c], Ya[c * 64 + r], acc);
        Yb[o * 64 + r] = fmaxf(acc, 0.0f);
    }
    __syncthreads();
    // L1: Yb -> Ya, relu
    #pragma unroll
    for (int k = 0; k < 8; ++k) {
        const int q = tid + TPB * k;
        const int o = q >> 6, r = q & 63;
        float acc = rb1[o];
        const float* wp = rw1 + o * 64;
        #pragma unroll 8
        for (int c = 0; c < 64; ++c) acc = fmaf(wp[c], Yb[c * 64 + r], acc);
        Ya[o * 64 + r] = fmaxf(acc, 0.0f);
    }
    __syncthreads();
    // L2: Ya -> Yb, linear
    #pragma unroll
    for (int k = 0; k < 8; ++k) {
        const int q = tid + TPB * k;
        const int o = q >> 6, r = q & 63;
        float acc = rb2[o];
        const float* wp = rw2 + o * 64;
        #pragma unroll 8
        for (int c = 0; c < 64; ++c) acc = fmaf(wp[c], Ya[c * 64 + r], acc);
        Yb[o * 64 + r] = acc;
    }
    __syncthreads();

    // coalesced store: out[n][r][o] = Yb[o][r]
    for (int q = tid; q < 4096; q += TPB) {
        const int r = q >> 6, o = q & 63;
        out[(n * 64 + r) * 64 + o] = Yb[o * 64 + r];
    }
}

extern "C" void kernel_launch(void* const* d_in, const int* in_sizes, int n_in,
                              void* d_out, int out_size, void* d_ws, size_t ws_size,
                              hipStream_t stream) {
    const int*   rpos  = (const int*)  d_in[0];
    const float* rooms = (const float*)d_in[1];
    const float* emb   = (const float*)d_in[2];
    const float* w0    = (const float*)d_in[3];
    const float* b0    = (const float*)d_in[4];
    const float* w1    = (const float*)d_in[5];
    const float* b1    = (const float*)d_in[6];
    const float* w2    = (const float*)d_in[7];
    const float* b2    = (const float*)d_in[8];
    const float* rw0   = (const float*)d_in[9];
    const float* rb0   = (const float*)d_in[10];
    const float* rw1   = (const float*)d_in[11];
    const float* rb1   = (const float*)d_in[12];
    const float* rw2   = (const float*)d_in[13];
    const float* rb2   = (const float*)d_in[14];
    float* out = (float*)d_out;

    const int n = in_sizes[0] / (R_ * 2);   // number of samples (512)
    hipLaunchKernelGGL(fused_mainnet, dim3(n), dim3(TPB), 0, stream,
                       rpos, rooms, emb, w0, b0, w1, b1, w2, b2,
                       rw0, rb0, rw1, rb1, rw2, rb2, out);
}

// Round 2
// 176.672 us; speedup vs baseline: 5.7790x; 5.7790x over previous
//
#include <hip/hip_runtime.h>
#include <stdint.h>

typedef short v8s __attribute__((ext_vector_type(8)));
typedef float v4f __attribute__((ext_vector_type(4)));

#define TPB 512

// ---- LDS layout (bytes) ----
// X1 : bf16 [32x][26y][32c]  rows 64B,  swz (row&3)<<4   @0       size 53,248  (phase B write, C read)
// X2 : bf16 [32x][26y][64c]  rows 128B, swz (row&7)<<4   @53,248  size 106,496 (C write, D read)
// X0 : bf16 [32x][28y][32c]  rows 64B,  swz (row&3)<<4   @102,400 size 57,344  (A write, B read)
// x0f: f32  [768][26]                                    @0       size 79,872  (A only)
// x3 : bf16 [768][32c]       rows 64B,  swz (row&3)<<4   @0       size 49,152  (D)
// Y  : f32  [64r][64c] swz rows 256B                     @0 /@16,384           (E)
#define X1_OFF 0
#define X2_OFF 53248
#define X0_OFF 102400
#define X3_OFF 0
#define YA_OFF 0
#define YB_OFF 16384
#define SMEM_BYTES 159744

// ws fragment bases (16B units): conv0 50 frags, conv1 36, conv2 72
#define WS0_U 0
#define WS1_U 3200
#define WS2_U 5504
#define WS_UNITS 10112

__device__ __forceinline__ uint16_t f2b(float f) {
    uint32_t u = __float_as_uint(f);
    return (uint16_t)((u + 0x7FFFu + ((u >> 16) & 1u)) >> 16);
}
__device__ __forceinline__ float b2f(uint16_t h) {
    return __uint_as_float(((uint32_t)h) << 16);
}

// ---------------- weight prep: pack A-fragments (bf16) into d_ws ----------------
// frag id layout: fid = (t*KF + kf)*MT_TOT + m ; lane l holds W[oc0+(l&15)][kf*32+(l>>4)*8 + j]
__global__ void prep_weights(const float* __restrict__ w0,
                             const float* __restrict__ w1,
                             const float* __restrict__ w2,
                             uint8_t* __restrict__ ws)
{
    int u = blockIdx.x * 256 + threadIdx.x;
    if (u >= WS_UNITS) return;
    int l = u & 63, fid = u >> 6;
    const float* src; int IC, KS_, t, kf, m;
    if (fid < 50)      { src = w0; IC = 26; KS_ = 5; t = fid >> 1; kf = 0; m = fid & 1; }
    else if (fid < 86) { int v = fid - 50; src = w1; IC = 32; KS_ = 3; t = v >> 2; kf = 0; m = v & 3; }
    else               { int v = fid - 86; src = w2; IC = 64; KS_ = 3; t = v >> 3; kf = (v >> 2) & 1; m = v & 3; }
    int oc = m * 16 + (l & 15);
    int kb = kf * 32 + ((l >> 4) * 8);
    int ky = t / KS_, kx = t - ky * KS_;
    v8s out;
#pragma unroll
    for (int j = 0; j < 8; ++j) {
        int k = kb + j;
        float v = (k < IC) ? src[((oc * IC + k) * KS_ + ky) * KS_ + kx] : 0.f;
        out[j] = (short)f2b(v);
    }
    ((v8s*)ws)[u] = out;
}

// ---------------- conv phase: tap-decomposed implicit GEMM on MFMA ----------------
template<int MT, int KF, int TAPS, int KS, int PAD,
         int IN_OFF, int IN_SH, int IN_ROWS,
         int OUT_OFF, int OUT_SH, int OUT_ROWS, int OUT_PAD,
         int WS_BASE, int MBASE, int MT_TOT>
__device__ __forceinline__ void conv_mfma(uint8_t* smem, const v8s* __restrict__ wsv,
                                          const float* __restrict__ bias, int tid)
{
    const int wv = tid >> 6, l = tid & 63;
    const int kg = l >> 4;           // 0..3 : k-subgroup of 8
    const int kgoff = kg << 4;       // byte offset of lane's 16B within k=0..31 block
    const int col = l & 15;          // pixel within N-tile
    constexpr int IN_MSK  = (IN_SH  == 7) ? 7 : 3;
    constexpr int OUT_MSK = (OUT_SH == 7) ? 7 : 3;

    int px[6], py[6];
#pragma unroll
    for (int i = 0; i < 6; ++i) {
        int p = (wv + 8 * i) * 16 + col;      // pixel 0..767
        int x = (p * 2731) >> 16;             // p / 24
        px[i] = x; py[i] = p - x * 24;
    }
    v4f acc[MT][6];
#pragma unroll
    for (int m = 0; m < MT; ++m)
#pragma unroll
        for (int i = 0; i < 6; ++i) acc[m][i] = (v4f){0.f, 0.f, 0.f, 0.f};

    for (int t = 0; t < TAPS; ++t) {
        const int ky = t / KS, kx = t - ky * KS;
        const int dx = ky - PAD, dy = kx - PAD;
        v8s af[MT][KF];
#pragma unroll
        for (int m = 0; m < MT; ++m)
#pragma unroll
            for (int kf = 0; kf < KF; ++kf)
                af[m][kf] = wsv[WS_BASE + ((t * KF + kf) * MT_TOT + MBASE + m) * 64 + l];
#pragma unroll
        for (int i = 0; i < 6; ++i) {
            int xi = px[i] + dx;
            int rowp = xi * IN_ROWS + (py[i] + dy + PAD);   // y handled by physical pad
            int a = ((rowp << IN_SH) | kgoff) ^ ((rowp & IN_MSK) << 4);
            a = ((unsigned)xi < 32u) ? a : kgoff;           // x OOB -> zeroed pad row 0
            a += IN_OFF;
            v8s b0 = *(const v8s*)(smem + a);
#pragma unroll
            for (int m = 0; m < MT; ++m)
                acc[m][i] = __builtin_amdgcn_mfma_f32_16x16x32_bf16(af[m][0], b0, acc[m][i], 0, 0, 0);
            if (KF == 2) {
                v8s b1 = *(const v8s*)(smem + (a ^ 64));    // k 32..63 half of the 128B row
#pragma unroll
                for (int m = 0; m < MT; ++m)
                    acc[m][i] = __builtin_amdgcn_mfma_f32_16x16x32_bf16(af[m][1], b1, acc[m][i], 0, 0, 0);
            }
        }
    }
    // epilogue: bias + relu + bf16 pack, b64 store (4 consecutive oc per lane)
#pragma unroll
    for (int m = 0; m < MT; ++m) {
        const float* bp = bias + (MBASE + m) * 16 + kg * 4;
        float bb0 = bp[0], bb1 = bp[1], bb2 = bp[2], bb3 = bp[3];
#pragma unroll
        for (int i = 0; i < 6; ++i) {
            float v0 = fmaxf(acc[m][i][0] + bb0, 0.f);
            float v1 = fmaxf(acc[m][i][1] + bb1, 0.f);
            float v2 = fmaxf(acc[m][i][2] + bb2, 0.f);
            float v3 = fmaxf(acc[m][i][3] + bb3, 0.f);
            uint2 pk;
            pk.x = (uint32_t)f2b(v0) | ((uint32_t)f2b(v1) << 16);
            pk.y = (uint32_t)f2b(v2) | ((uint32_t)f2b(v3) << 16);
            int rowp = px[i] * OUT_ROWS + py[i] + OUT_PAD;
            int coff = m * 32 + kg * 8;
            int a = OUT_OFF + ((((rowp << OUT_SH) | coff)) ^ ((rowp & OUT_MSK) << 4));
            *(uint2*)(smem + a) = pk;
        }
    }
}

// ---------------- gather one conv2 half into registers ----------------
__device__ __forceinline__ void gather_half(const uint8_t* smem,
                                            const float* __restrict__ rooms,
                                            const int* __restrict__ rp,
                                            int gr, int gg, int h, float* yreg)
{
    if ((gg >> 2) != h) return;
    const int gl = gg & 3;                    // 8-channel group within half
    const int pxr = rp[gr * 2], pyr = rp[gr * 2 + 1];
    const float* rr = rooms + gr * 324;       // mask channel of room gr
    float s0=0,s1=0,s2=0,s3=0,s4=0,s5=0,s6=0,s7=0;
#pragma unroll
    for (int ci = 0; ci < 6; ++ci)
#pragma unroll
        for (int cj = 0; cj < 6; ++cj) {
            float mv = rr[ci * 6 + cj];
            if (mv != 0.f) {
                int p = (pxr + ci) * 24 + pyr + cj;
                int a = X3_OFF + (((p << 6) | (gl << 4)) ^ ((p & 3) << 4));
                v8s v = *(const v8s*)(smem + a);
                s0 = fmaf(b2f((uint16_t)v[0]), mv, s0);
                s1 = fmaf(b2f((uint16_t)v[1]), mv, s1);
                s2 = fmaf(b2f((uint16_t)v[2]), mv, s2);
                s3 = fmaf(b2f((uint16_t)v[3]), mv, s3);
                s4 = fmaf(b2f((uint16_t)v[4]), mv, s4);
                s5 = fmaf(b2f((uint16_t)v[5]), mv, s5);
                s6 = fmaf(b2f((uint16_t)v[6]), mv, s6);
                s7 = fmaf(b2f((uint16_t)v[7]), mv, s7);
            }
        }
    yreg[0]=s0; yreg[1]=s1; yreg[2]=s2; yreg[3]=s3;
    yreg[4]=s4; yreg[5]=s5; yreg[6]=s6; yreg[7]=s7;
}

// ---------------- MLP layer (f32, per-thread dot, wave-uniform weight rows) ----------------
template<bool RELU, bool TOGLOBAL>
__device__ __forceinline__ void mlp_layer(uint8_t* smem, int inoff, int outoff,
                                          const float* __restrict__ W,
                                          const float* __restrict__ bias,
                                          float* __restrict__ outg, int tid)
{
    const int og = tid >> 6, r = tid & 63;
    const int ogs = __builtin_amdgcn_readfirstlane(og);
    const int swz = (r & 7) << 4;
    float yrow[64];
#pragma unroll
    for (int cg = 0; cg < 16; ++cg) {
        v4f v = *(const v4f*)(smem + inoff + ((r * 256 + cg * 16) ^ swz));
        yrow[cg*4+0] = v[0]; yrow[cg*4+1] = v[1]; yrow[cg*4+2] = v[2]; yrow[cg*4+3] = v[3];
    }
    float acc[8];
    const float* Wb = W + ogs * 8 * 64;
#pragma unroll
    for (int oo = 0; oo < 8; ++oo) {
        float a = bias[ogs * 8 + oo];
        const float* wr = Wb + oo * 64;
#pragma unroll
        for (int c = 0; c < 64; ++c) a = fmaf(wr[c], yrow[c], a);
        acc[oo] = RELU ? fmaxf(a, 0.f) : a;
    }
    v4f o0 = {acc[0],acc[1],acc[2],acc[3]}, o1 = {acc[4],acc[5],acc[6],acc[7]};
    if (TOGLOBAL) {
        *(v4f*)(outg + r * 64 + ogs * 8) = o0;
        *(v4f*)(outg + r * 64 + ogs * 8 + 4) = o1;
    } else {
        *(v4f*)(smem + outoff + ((r * 256 + og * 32) ^ swz)) = o0;
        *(v4f*)(smem + outoff + ((r * 256 + og * 32 + 16) ^ swz)) = o1;
    }
}

// ---------------- fused main kernel: one block per sample ----------------
__global__ __launch_bounds__(TPB, 2)
void fused_main(const int* __restrict__ rpos,
                const float* __restrict__ rooms,
                const float* __restrict__ emb,
                const float* __restrict__ b0, const float* __restrict__ b1,
                const float* __restrict__ b2,
                const float* __restrict__ rw0, const float* __restrict__ rb0,
                const float* __restrict__ rw1, const float* __restrict__ rb1,
                const float* __restrict__ rw2, const float* __restrict__ rb2,
                const uint8_t* __restrict__ ws,
                float* __restrict__ out)
{
    __shared__ __align__(16) uint8_t smem[SMEM_BYTES];
    const int tid = threadIdx.x, n = blockIdx.x;
    const int* rp = rpos + n * 128;
    const v8s* wsv = (const v8s*)ws;
    float* x0f = (float*)smem;

    // P1: zero scatter buffer
    for (int q = tid; q < 768 * 26; q += TPB) x0f[q] = 0.f;
    __syncthreads();
    // P2: background channel + atomic scatter (channel-last)
    for (int q = tid; q < 768; q += TPB) x0f[q * 26 + 9] = 1.f;
    for (int q = tid; q < 2304; q += TPB) {
        int r = (q * 1821) >> 16;                 // q / 36
        int cell = q - r * 36;
        const float* rr = rooms + r * 324;
        float mval = rr[cell];
        if (mval != 0.f) {
            int ci = cell / 6, cj = cell - ci * 6;
            int p = (rp[r * 2] + ci) * 24 + rp[r * 2 + 1] + cj;
            float* dst = x0f + p * 26;
#pragma unroll
            for (int c = 0; c < 9; ++c) {
                float v = rr[c * 36 + cell];
                if (v != 0.f) atomicAdd(dst + c, v);
            }
            const float* er = emb + r * 16;
#pragma unroll
            for (int e = 0; e < 16; ++e) atomicAdd(dst + 10 + e, er[e] * mval);
        }
    }
    __syncthreads();
    // P3: convert to channel-last bf16 X0 (y-padded by 2, ch padded to 32, swizzled)
    for (int u = tid; u < 896 * 4; u += TPB) {
        int row = u >> 2, cg = u & 3;
        int x = (row * 2341) >> 16, y = row - x * 28;   // row / 28
        v8s o = {0,0,0,0,0,0,0,0};
        if (y >= 2 && y < 26) {
            int p = x * 24 + y - 2;
            const float* sp = x0f + p * 26 + cg * 8;
#pragma unroll
            for (int j = 0; j < 8; ++j) {
                int c = cg * 8 + j;
                float v = (c < 26) ? sp[j] : 0.f;
                o[j] = (short)f2b(v);
            }
        }
        int a = X0_OFF + (((row << 6) | (cg << 4)) ^ ((row & 3) << 4));
        *(v8s*)(smem + a) = o;
    }
    __syncthreads();
    // P4: zero X1 y-pad rows, then conv0 (26->32, 5x5)
    if (tid < 256) {
        int rowi = tid >> 2, slot = tid & 3;
        int x = rowi >> 1, rowp = x * 26 + ((rowi & 1) ? 25 : 0);
        *(v8s*)(smem + X1_OFF + ((rowp << 6) | (slot << 4))) = (v8s){0,0,0,0,0,0,0,0};
    }
    conv_mfma<2,1,25,5,2, X0_OFF,6,28, X1_OFF,6,26,1, WS0_U,0,2>(smem, wsv, b0, tid);
    __syncthreads();
    // P5: zero X2 y-pad rows, then conv1 (32->64, 3x3)
    {
        int rowi = tid >> 3, slot = tid & 7;
        int x = rowi >> 1, rowp = x * 26 + ((rowi & 1) ? 25 : 0);
        *(v8s*)(smem + X2_OFF + ((rowp << 7) | (slot << 4))) = (v8s){0,0,0,0,0,0,0,0};
    }
    conv_mfma<4,1,9,3,1, X1_OFF,6,26, X2_OFF,7,26,1, WS1_U,0,4>(smem, wsv, b1, tid);
    __syncthreads();
    // P6..P9: conv2 (64->64, 3x3) in two oc-halves, each fused with room gather
    float yreg[8];
    const int gr = tid >> 3, gg = tid & 7;
    conv_mfma<2,2,9,3,1, X2_OFF,7,26, X3_OFF,6,24,0, WS2_U,0,4>(smem, wsv, b2, tid);
    __syncthreads();
    gather_half(smem, rooms, rp, gr, gg, 0, yreg);
    __syncthreads();
    conv_mfma<2,2,9,3,1, X2_OFF,7,26, X3_OFF,6,24,0, WS2_U,2,4>(smem, wsv, b2, tid);
    __syncthreads();
    gather_half(smem, rooms, rp, gr, gg, 1, yreg);
    __syncthreads();
    // P10: assemble Y f32 [r][c] (swizzled rows)
    {
        int base = gr * 256 + gg * 32;
        int swz = (gr & 7) << 4;
        v4f a0 = {yreg[0], yreg[1], yreg[2], yreg[3]};
        v4f a1 = {yreg[4], yreg[5], yreg[6], yreg[7]};
        *(v4f*)(smem + YA_OFF + ((base) ^ swz)) = a0;
        *(v4f*)(smem + YA_OFF + ((base + 16) ^ swz)) = a1;
    }
    __syncthreads();
    // P11: 3-layer room MLP (f32)
    mlp_layer<true,  false>(smem, YA_OFF, YB_OFF, rw0, rb0, nullptr, tid);
    __syncthreads();
    mlp_layer<true,  false>(smem, YB_OFF, YA_OFF, rw1, rb1, nullptr, tid);
    __syncthreads();
    mlp_layer<false, true >(smem, YA_OFF, 0, rw2, rb2, out + n * 4096, tid);
}

extern "C" void kernel_launch(void* const* d_in, const int* in_sizes, int n_in,
                              void* d_out, int out_size, void* d_ws, size_t ws_size,
                              hipStream_t stream) {
    const int*   rpos  = (const int*)  d_in[0];
    const float* rooms = (const float*)d_in[1];
    const float* emb   = (const float*)d_in[2];
    const float* w0    = (const float*)d_in[3];
    const float* b0    = (const float*)d_in[4];
    const float* w1    = (const float*)d_in[5];
    const float* b1    = (const float*)d_in[6];
    const float* w2    = (const float*)d_in[7];
    const float* b2    = (const float*)d_in[8];
    const float* rw0   = (const float*)d_in[9];
    const float* rb0   = (const float*)d_in[10];
    const float* rw1   = (const float*)d_in[11];
    const float* rb1   = (const float*)d_in[12];
    const float* rw2   = (const float*)d_in[13];
    const float* rb2   = (const float*)d_in[14];
    float* out = (float*)d_out;
    uint8_t* ws = (uint8_t*)d_ws;

    const int n = in_sizes[0] / 128;   // samples (512)
    hipLaunchKernelGGL(prep_weights, dim3((WS_UNITS + 255) / 256), dim3(256), 0, stream,
                       w0, w1, w2, ws);
    hipLaunchKernelGGL(fused_main, dim3(n), dim3(TPB), 0, stream,
                       rpos, rooms, emb, b0, b1, b2,
                       rw0, rb0, rw1, rb1, rw2, rb2, ws, out);
}

// Round 3
// 134.026 us; speedup vs baseline: 7.6178x; 1.3182x over previous
//
#include <hip/hip_runtime.h>
#include <stdint.h>

typedef short v8s __attribute__((ext_vector_type(8)));
typedef float v4f __attribute__((ext_vector_type(4)));

#define TPB 1024

// ---- LDS layout (bytes) ----
// scatter : X0 bf16 [32x][28y][32c] rows 64B swz(row&3)<<4   @0        57,344
// conv0   : X0 -> X1 bf16 [32x][26y][32c] rows 64B           @106,496  53,248 (ends 159,744)
// conv1   : X1 -> X2 bf16 [32x][26y][64c] rows 128B swz&7    @0       106,496 (X0 dead)
// conv2   : X2 -> X3 bf16 [768p][32c] rows 64B swz&3         @106,496  49,152 (X1 dead)
// MLP     : Ya f32 @0 (16,384), Yb f32 @16,384 (16,384)               (X2 dead)
#define X0_OFF 0
#define X1_OFF 106496
#define X2_OFF 0
#define X3_OFF 106496
#define YA_OFF 0
#define YB_OFF 16384
#define SMEM_BYTES 159744

// ws fragment bases (16B units): conv0 50 frags, conv1 36, conv2 72 (x64 lanes)
#define WS0_U 0
#define WS1_U 3200
#define WS2_U 5504
#define WS_UNITS 10112

__device__ __forceinline__ uint16_t f2b(float f) {
    uint32_t u = __float_as_uint(f);
    return (uint16_t)((u + 0x7FFFu + ((u >> 16) & 1u)) >> 16);
}
__device__ __forceinline__ float b2f(uint16_t h) {
    return __uint_as_float(((uint32_t)h) << 16);
}

// ---------------- weight prep: pack A-fragments (bf16) into d_ws ----------------
// fid = (t*KF + kf)*MT_TOT + m ; lane l holds W[m*16+(l&15)][kf*32+(l>>4)*8 + j]
__global__ void prep_weights(const float* __restrict__ w0,
                             const float* __restrict__ w1,
                             const float* __restrict__ w2,
                             uint8_t* __restrict__ ws)
{
    int u = blockIdx.x * 256 + threadIdx.x;
    if (u >= WS_UNITS) return;
    int l = u & 63, fid = u >> 6;
    const float* src; int IC, KS_, t, kf, m;
    if (fid < 50)      { src = w0; IC = 26; KS_ = 5; t = fid >> 1; kf = 0; m = fid & 1; }
    else if (fid < 86) { int v = fid - 50; src = w1; IC = 32; KS_ = 3; t = v >> 2; kf = 0; m = v & 3; }
    else               { int v = fid - 86; src = w2; IC = 64; KS_ = 3; t = v >> 3; kf = (v >> 2) & 1; m = v & 3; }
    int oc = m * 16 + (l & 15);
    int kb = kf * 32 + ((l >> 4) * 8);
    int ky = t / KS_, kx = t - ky * KS_;
    v8s out;
#pragma unroll
    for (int j = 0; j < 8; ++j) {
        int k = kb + j;
        float v = (k < IC) ? src[((oc * IC + k) * KS_ + ky) * KS_ + kx] : 0.f;
        out[j] = (short)f2b(v);
    }
    ((v8s*)ws)[u] = out;
}

// ---------------- conv core: tap-decomposed implicit GEMM on MFMA ----------------
template<int MT, int KF, int TAPS, int KS, int PAD,
         int IN_OFF, int IN_SH, int IN_ROWS, int WS_BASE, int MT_TOT>
__device__ __forceinline__ void conv_core(const uint8_t* smem, const v8s* __restrict__ wsv,
                                          int l, const int* px, const int* py,
                                          v4f (&acc)[MT][3])
{
    const int kgoff = ((l >> 4) << 4);
    constexpr int MSK = (IN_SH == 7) ? 7 : 3;
    for (int t = 0; t < TAPS; ++t) {
        const int ky = t / KS, kx = t - ky * KS;
        const int dx = ky - PAD, dy = kx - PAD;
        v8s af[MT][KF];
#pragma unroll
        for (int m = 0; m < MT; ++m)
#pragma unroll
            for (int kf = 0; kf < KF; ++kf)
                af[m][kf] = wsv[WS_BASE + ((t * KF + kf) * MT_TOT + m) * 64 + l];
#pragma unroll
        for (int i = 0; i < 3; ++i) {
            const int xi = px[i] + dx;
            const int rowp = xi * IN_ROWS + py[i] + dy + PAD;   // y via physical pad
            int a = ((rowp << IN_SH) | kgoff) ^ ((rowp & MSK) << 4);
            a = ((unsigned)xi < 32u) ? a : kgoff;               // x OOB -> zeroed row 0
            a += IN_OFF;
            const v8s bf0 = *(const v8s*)(smem + a);
#pragma unroll
            for (int m = 0; m < MT; ++m)
                acc[m][i] = __builtin_amdgcn_mfma_f32_16x16x32_bf16(af[m][0], bf0, acc[m][i], 0, 0, 0);
            if (KF == 2) {
                const v8s bf1 = *(const v8s*)(smem + (a ^ 64));
#pragma unroll
                for (int m = 0; m < MT; ++m)
                    acc[m][i] = __builtin_amdgcn_mfma_f32_16x16x32_bf16(af[m][1], bf1, acc[m][i], 0, 0, 0);
            }
        }
    }
}

// ---------------- conv epilogue: bias+relu+bf16 pack, packed b64 stores ----------------
template<int MTOT, int M0, int M1, int OUT_OFF, int OUT_SH, int OUT_ROWS, int OUT_PAD>
__device__ __forceinline__ void conv_epi(uint8_t* smem, const float* __restrict__ bias,
                                         v4f (&acc)[MTOT][3], const int* px, const int* py, int kg)
{
    constexpr int MSK = (OUT_SH == 7) ? 7 : 3;
#pragma unroll
    for (int m = M0; m < M1; ++m) {
        const float* bp = bias + m * 16 + kg * 4;
        const float bb0 = bp[0], bb1 = bp[1], bb2 = bp[2], bb3 = bp[3];
#pragma unroll
        for (int i = 0; i < 3; ++i) {
            const float v0 = fmaxf(acc[m][i][0] + bb0, 0.f);
            const float v1 = fmaxf(acc[m][i][1] + bb1, 0.f);
            const float v2 = fmaxf(acc[m][i][2] + bb2, 0.f);
            const float v3 = fmaxf(acc[m][i][3] + bb3, 0.f);
            uint2 pk;
            pk.x = (uint32_t)f2b(v0) | ((uint32_t)f2b(v1) << 16);
            pk.y = (uint32_t)f2b(v2) | ((uint32_t)f2b(v3) << 16);
            const int rowp = px[i] * OUT_ROWS + py[i] + OUT_PAD;
            const int coff = (m - M0) * 32 + (kg << 3);
            const int a = OUT_OFF + (((rowp << OUT_SH) | coff) ^ ((rowp & MSK) << 4));
            *(uint2*)(smem + a) = pk;
        }
    }
}

// ---------------- gather one conv2 half into registers (threads < 512) ----------------
__device__ __forceinline__ void gather_half(const uint8_t* smem,
                                            const float* __restrict__ rooms,
                                            const int* __restrict__ rp,
                                            int gr, int gg, int h, float* yreg)
{
    if ((gg >> 2) != h) return;
    const int gl = gg & 3;
    const int pxr = rp[gr * 2], pyr = rp[gr * 2 + 1];
    const float* rr = rooms + gr * 324;
    float s0=0,s1=0,s2=0,s3=0,s4=0,s5=0,s6=0,s7=0;
#pragma unroll
    for (int ci = 0; ci < 6; ++ci)
#pragma unroll
        for (int cj = 0; cj < 6; ++cj) {
            const float mv = rr[ci * 6 + cj];
            if (mv != 0.f) {
                const int p = (pxr + ci) * 24 + pyr + cj;
                const int a = X3_OFF + (((p << 6) | (gl << 4)) ^ ((p & 3) << 4));
                const v8s v = *(const v8s*)(smem + a);
                s0 = fmaf(b2f((uint16_t)v[0]), mv, s0);
                s1 = fmaf(b2f((uint16_t)v[1]), mv, s1);
                s2 = fmaf(b2f((uint16_t)v[2]), mv, s2);
                s3 = fmaf(b2f((uint16_t)v[3]), mv, s3);
                s4 = fmaf(b2f((uint16_t)v[4]), mv, s4);
                s5 = fmaf(b2f((uint16_t)v[5]), mv, s5);
                s6 = fmaf(b2f((uint16_t)v[6]), mv, s6);
                s7 = fmaf(b2f((uint16_t)v[7]), mv, s7);
            }
        }
    yreg[0]=s0; yreg[1]=s1; yreg[2]=s2; yreg[3]=s3;
    yreg[4]=s4; yreg[5]=s5; yreg[6]=s6; yreg[7]=s7;
}

// ---------------- MLP layer (f32), 1024 threads: 4 outputs each ----------------
template<bool RELU, bool TOGLOBAL>
__device__ __forceinline__ void mlp_layer(uint8_t* smem, int inoff, int outoff,
                                          const float* __restrict__ W,
                                          const float* __restrict__ bias,
                                          float* __restrict__ outg, int tid)
{
    const int og = tid >> 6, r = tid & 63;
    const int ogs = __builtin_amdgcn_readfirstlane(og);
    const int swz = (r & 7) << 4;
    float yrow[64];
#pragma unroll
    for (int cg = 0; cg < 16; ++cg) {
        v4f v = *(const v4f*)(smem + inoff + ((r * 256 + cg * 16) ^ swz));
        yrow[cg*4+0] = v[0]; yrow[cg*4+1] = v[1]; yrow[cg*4+2] = v[2]; yrow[cg*4+3] = v[3];
    }
    float acc[4];
    const float* Wb = W + ogs * 4 * 64;
#pragma unroll
    for (int oo = 0; oo < 4; ++oo) {
        float a = bias[ogs * 4 + oo];
        const float* wr = Wb + oo * 64;
#pragma unroll
        for (int c = 0; c < 64; ++c) a = fmaf(wr[c], yrow[c], a);
        acc[oo] = RELU ? fmaxf(a, 0.f) : a;
    }
    v4f o0 = {acc[0], acc[1], acc[2], acc[3]};
    if (TOGLOBAL) *(v4f*)(outg + r * 64 + ogs * 4) = o0;
    else          *(v4f*)(smem + outoff + ((r * 256 + ogs * 16) ^ swz)) = o0;
}

// ---------------- fused main kernel: one block (16 waves) per sample ----------------
__global__ __launch_bounds__(TPB)
void fused_main(const int* __restrict__ rpos,
                const float* __restrict__ rooms,
                const float* __restrict__ emb,
                const float* __restrict__ b0, const float* __restrict__ b1,
                const float* __restrict__ b2,
                const float* __restrict__ rw0, const float* __restrict__ rb0,
                const float* __restrict__ rw1, const float* __restrict__ rb1,
                const float* __restrict__ rw2, const float* __restrict__ rb2,
                const uint8_t* __restrict__ ws,
                float* __restrict__ out)
{
    __shared__ __align__(16) uint8_t smem[SMEM_BYTES];
    const int tid = threadIdx.x, n = blockIdx.x;
    const int* rp = rpos + n * 128;
    const v8s* wsv = (const v8s*)ws;

    // ---- P1: register scatter -> bf16 X0 (no atomics, no f32 buffer) ----
    if (tid < 768) {
        const int x = (tid * 2731) >> 16;       // tid / 24
        const int y = tid - x * 24;
        float a[26];
#pragma unroll
        for (int c = 0; c < 26; ++c) a[c] = 0.f;
        a[9] = 1.f;                              // background channel
        for (int r = 0; r < 64; ++r) {
            const int ci = x - rp[2 * r], cj = y - rp[2 * r + 1];
            if ((unsigned)ci < 6u && (unsigned)cj < 6u) {
                const int cell = ci * 6 + cj;
                const float* rr = rooms + r * 324;
                const float m = rr[cell];
                if (m != 0.f) {
#pragma unroll
                    for (int c = 0; c < 9; ++c) a[c] += rr[c * 36 + cell];
                    const float* er = emb + r * 16;
#pragma unroll
                    for (int e = 0; e < 16; ++e) a[10 + e] = fmaf(er[e], m, a[10 + e]);
                }
            }
        }
        const int row = x * 28 + y + 2;
        const int swz = (row & 3) << 4;
#pragma unroll
        for (int cg = 0; cg < 4; ++cg) {
            v8s o;
#pragma unroll
            for (int j = 0; j < 8; ++j) {
                const int c = cg * 8 + j;
                o[j] = (short)((c < 26) ? f2b(a[c]) : (uint16_t)0);
            }
            *(v8s*)(smem + X0_OFF + (((row << 6) | (cg << 4)) ^ swz)) = o;
        }
    } else {
        // zero X0 y-pad rows: 128 rows x 4 slots, 256 threads x 2
        const int base = (tid - 768) * 2;
#pragma unroll
        for (int k = 0; k < 2; ++k) {
            const int u = base + k;
            const int rowi = u >> 2, slot = u & 3;
            const int x = rowi >> 2, yp = rowi & 3;
            const int row = x * 28 + ((yp < 2) ? yp : yp + 24);
            *(v8s*)(smem + X0_OFF + (((row << 6) | (slot << 4)) ^ ((row & 3) << 4))) =
                (v8s){0,0,0,0,0,0,0,0};
        }
    }
    __syncthreads();

    // per-thread MFMA geometry
    const int l = tid & 63, wv = tid >> 6, kg = l >> 4;
    int px[3], py[3];
#pragma unroll
    for (int i = 0; i < 3; ++i) {
        const int p = (wv + 16 * i) * 16 + (l & 15);
        const int x = (p * 2731) >> 16;
        px[i] = x; py[i] = p - x * 24;
    }

    // ---- P2: conv0 (26->32, 5x5) + X1 pad zero ----
    {
        if (tid < 256) {
            const int rowi = tid >> 2, slot = tid & 3;
            const int x = rowi >> 1;
            const int rowp = x * 26 + ((rowi & 1) ? 25 : 0);
            *(v8s*)(smem + X1_OFF + (((rowp << 6) | (slot << 4)) ^ ((rowp & 3) << 4))) =
                (v8s){0,0,0,0,0,0,0,0};
        }
        v4f acc[2][3];
#pragma unroll
        for (int m = 0; m < 2; ++m)
#pragma unroll
            for (int i = 0; i < 3; ++i) acc[m][i] = (v4f){0.f,0.f,0.f,0.f};
        conv_core<2,1,25,5,2, X0_OFF,6,28, WS0_U,2>(smem, wsv, l, px, py, acc);
        conv_epi<2,0,2, X1_OFF,6,26,1>(smem, b0, acc, px, py, kg);
    }
    __syncthreads();

    // ---- P3: conv1 (32->64, 3x3) + X2 pad zero ----
    {
        if (tid < 512) {
            const int rowi = tid >> 3, slot = tid & 7;
            const int x = rowi >> 1;
            const int rowp = x * 26 + ((rowi & 1) ? 25 : 0);
            *(v8s*)(smem + X2_OFF + (((rowp << 7) | (slot << 4)) ^ ((rowp & 7) << 4))) =
                (v8s){0,0,0,0,0,0,0,0};
        }
        v4f acc[4][3];
#pragma unroll
        for (int m = 0; m < 4; ++m)
#pragma unroll
            for (int i = 0; i < 3; ++i) acc[m][i] = (v4f){0.f,0.f,0.f,0.f};
        conv_core<4,1,9,3,1, X1_OFF,6,26, WS1_U,4>(smem, wsv, l, px, py, acc);
        conv_epi<4,0,4, X2_OFF,7,26,1>(smem, b1, acc, px, py, kg);
    }
    __syncthreads();

    // ---- P4: conv2 (64->64, 3x3) single K-sweep, two-stage epilogue + gather ----
    float yreg[8];
    {
        v4f acc[4][3];
#pragma unroll
        for (int m = 0; m < 4; ++m)
#pragma unroll
            for (int i = 0; i < 3; ++i) acc[m][i] = (v4f){0.f,0.f,0.f,0.f};
        conv_core<4,2,9,3,1, X2_OFF,7,26, WS2_U,4>(smem, wsv, l, px, py, acc);
        // half 0 (oc 0..31): X3 write does not touch X2, no barrier needed first
        conv_epi<4,0,2, X3_OFF,6,24,0>(smem, b2, acc, px, py, kg);
        __syncthreads();
        if (tid < 512) gather_half(smem, rooms, rp, tid >> 3, tid & 7, 0, yreg);
        __syncthreads();
        // half 1 (oc 32..63)
        conv_epi<4,2,4, X3_OFF,6,24,0>(smem, b2, acc, px, py, kg);
        __syncthreads();
        if (tid < 512) gather_half(smem, rooms, rp, tid >> 3, tid & 7, 1, yreg);
        __syncthreads();
    }

    // ---- P5: assemble Y f32 [r][c] (swizzled rows); thread (gr,gg) holds Y[gr][gg*8..+8]
    if (tid < 512) {
        const int gr = tid >> 3, gg = tid & 7;
        const int base = gr * 256 + gg * 32;
        const int swz = (gr & 7) << 4;
        *(v4f*)(smem + YA_OFF + (base ^ swz))        = (v4f){yreg[0], yreg[1], yreg[2], yreg[3]};
        *(v4f*)(smem + YA_OFF + ((base + 16) ^ swz)) = (v4f){yreg[4], yreg[5], yreg[6], yreg[7]};
    }
    __syncthreads();

    // ---- P6: 3-layer room MLP (f32) ----
    mlp_layer<true,  false>(smem, YA_OFF, YB_OFF, rw0, rb0, nullptr, tid);
    __syncthreads();
    mlp_layer<true,  false>(smem, YB_OFF, YA_OFF, rw1, rb1, nullptr, tid);
    __syncthreads();
    mlp_layer<false, true >(smem, YA_OFF, 0, rw2, rb2, out + n * 4096, tid);
}

extern "C" void kernel_launch(void* const* d_in, const int* in_sizes, int n_in,
                              void* d_out, int out_size, void* d_ws, size_t ws_size,
                              hipStream_t stream) {
    const int*   rpos  = (const int*)  d_in[0];
    const float* rooms = (const float*)d_in[1];
    const float* emb   = (const float*)d_in[2];
    const float* w0    = (const float*)d_in[3];
    const float* b0    = (const float*)d_in[4];
    const float* w1    = (const float*)d_in[5];
    const float* b1    = (const float*)d_in[6];
    const float* w2    = (const float*)d_in[7];
    const float* b2    = (const float*)d_in[8];
    const float* rw0   = (const float*)d_in[9];
    const float* rb0   = (const float*)d_in[10];
    const float* rw1   = (const float*)d_in[11];
    const float* rb1   = (const float*)d_in[12];
    const float* rw2   = (const float*)d_in[13];
    const float* rb2   = (const float*)d_in[14];
    float* out = (float*)d_out;
    uint8_t* ws = (uint8_t*)d_ws;

    const int n = in_sizes[0] / 128;   // samples (512)
    hipLaunchKernelGGL(prep_weights, dim3((WS_UNITS + 255) / 256), dim3(256), 0, stream,
                       w0, w1, w2, ws);
    hipLaunchKernelGGL(fused_main, dim3(n), dim3(TPB), 0, stream,
                       rpos, rooms, emb, b0, b1, b2,
                       rw0, rb0, rw1, rb1, rw2, rb2, ws, out);
}

// Round 4
// 132.717 us; speedup vs baseline: 7.6930x; 1.0099x over previous
//
#include <hip/hip_runtime.h>
#include <stdint.h>

typedef short v8s __attribute__((ext_vector_type(8)));
typedef float v4f __attribute__((ext_vector_type(4)));

#define TPB 1024

// ---- LDS layout (bytes) ----
// scatter : X0 bf16 [32x][28y][32c] rows 64B swz(row&3)<<4   @0        57,344
// conv0   : X0 -> X1 bf16 [32x][26y][32c] rows 64B           @106,496  53,248 (ends 159,744)
// conv1   : X1 -> X2 bf16 [32x][26y][64c] rows 128B swz&7    @0       106,496 (X0 dead)
// conv2   : X2 -> X3 bf16 [768p][32c] rows 64B swz&3         @106,496  49,152 (X1 dead)
// MLP     : Ya f32 @0 (16,384), Yb f32 @16,384 (16,384)               (X2 dead)
#define X0_OFF 0
#define X1_OFF 106496
#define X2_OFF 0
#define X3_OFF 106496
#define YA_OFF 0
#define YB_OFF 16384
#define SMEM_BYTES 159744

// ws fragment bases (16B units): conv0 50 frags, conv1 36, conv2 72 (x64 lanes)
#define WS0_U 0
#define WS1_U 3200
#define WS2_U 5504
#define WS_UNITS 10112

__device__ __forceinline__ uint16_t f2b(float f) {
    uint32_t u = __float_as_uint(f);
    return (uint16_t)((u + 0x7FFFu + ((u >> 16) & 1u)) >> 16);
}
__device__ __forceinline__ float b2f(uint16_t h) {
    return __uint_as_float(((uint32_t)h) << 16);
}

// ---------------- weight prep: pack A-fragments (bf16) into d_ws ----------------
// fid = (t*KF + kf)*MT_TOT + m ; lane l holds W[m*16+(l&15)][kf*32+(l>>4)*8 + j]
__global__ void prep_weights(const float* __restrict__ w0,
                             const float* __restrict__ w1,
                             const float* __restrict__ w2,
                             uint8_t* __restrict__ ws)
{
    int u = blockIdx.x * 256 + threadIdx.x;
    if (u >= WS_UNITS) return;
    int l = u & 63, fid = u >> 6;
    const float* src; int IC, KS_, t, kf, m;
    if (fid < 50)      { src = w0; IC = 26; KS_ = 5; t = fid >> 1; kf = 0; m = fid & 1; }
    else if (fid < 86) { int v = fid - 50; src = w1; IC = 32; KS_ = 3; t = v >> 2; kf = 0; m = v & 3; }
    else               { int v = fid - 86; src = w2; IC = 64; KS_ = 3; t = v >> 3; kf = (v >> 2) & 1; m = v & 3; }
    int oc = m * 16 + (l & 15);
    int kb = kf * 32 + ((l >> 4) * 8);
    int ky = t / KS_, kx = t - ky * KS_;
    v8s out;
#pragma unroll
    for (int j = 0; j < 8; ++j) {
        int k = kb + j;
        float v = (k < IC) ? src[((oc * IC + k) * KS_ + ky) * KS_ + kx] : 0.f;
        out[j] = (short)f2b(v);
    }
    ((v8s*)ws)[u] = out;
}

// ---------------- conv core: tap-decomposed implicit GEMM on MFMA ----------------
template<int MT, int KF, int TAPS, int KS, int PAD,
         int IN_OFF, int IN_SH, int IN_ROWS, int WS_BASE, int MT_TOT>
__device__ __forceinline__ void conv_core(const uint8_t* smem, const v8s* __restrict__ wsv,
                                          int l, const int* px, const int* py,
                                          v4f (&acc)[MT][3])
{
    const int kgoff = ((l >> 4) << 4);
    constexpr int MSK = (IN_SH == 7) ? 7 : 3;
    for (int t = 0; t < TAPS; ++t) {
        const int ky = t / KS, kx = t - ky * KS;
        const int dx = ky - PAD, dy = kx - PAD;
        v8s af[MT][KF];
#pragma unroll
        for (int m = 0; m < MT; ++m)
#pragma unroll
            for (int kf = 0; kf < KF; ++kf)
                af[m][kf] = wsv[WS_BASE + ((t * KF + kf) * MT_TOT + m) * 64 + l];
#pragma unroll
        for (int i = 0; i < 3; ++i) {
            const int xi = px[i] + dx;
            const int rowp = xi * IN_ROWS + py[i] + dy + PAD;   // y via physical pad
            int a = ((rowp << IN_SH) | kgoff) ^ ((rowp & MSK) << 4);
            a = ((unsigned)xi < 32u) ? a : kgoff;               // x OOB -> zeroed row 0
            a += IN_OFF;
            const v8s bf0 = *(const v8s*)(smem + a);
#pragma unroll
            for (int m = 0; m < MT; ++m)
                acc[m][i] = __builtin_amdgcn_mfma_f32_16x16x32_bf16(af[m][0], bf0, acc[m][i], 0, 0, 0);
            if (KF == 2) {
                const v8s bf1 = *(const v8s*)(smem + (a ^ 64));
#pragma unroll
                for (int m = 0; m < MT; ++m)
                    acc[m][i] = __builtin_amdgcn_mfma_f32_16x16x32_bf16(af[m][1], bf1, acc[m][i], 0, 0, 0);
            }
        }
    }
}

// ---------------- conv epilogue: bias+relu+bf16 pack, packed b64 stores ----------------
template<int MTOT, int M0, int M1, int OUT_OFF, int OUT_SH, int OUT_ROWS, int OUT_PAD>
__device__ __forceinline__ void conv_epi(uint8_t* smem, const float* __restrict__ bias,
                                         v4f (&acc)[MTOT][3], const int* px, const int* py, int kg)
{
    constexpr int MSK = (OUT_SH == 7) ? 7 : 3;
#pragma unroll
    for (int m = M0; m < M1; ++m) {
        const float* bp = bias + m * 16 + kg * 4;
        const float bb0 = bp[0], bb1 = bp[1], bb2 = bp[2], bb3 = bp[3];
#pragma unroll
        for (int i = 0; i < 3; ++i) {
            const float v0 = fmaxf(acc[m][i][0] + bb0, 0.f);
            const float v1 = fmaxf(acc[m][i][1] + bb1, 0.f);
            const float v2 = fmaxf(acc[m][i][2] + bb2, 0.f);
            const float v3 = fmaxf(acc[m][i][3] + bb3, 0.f);
            uint2 pk;
            pk.x = (uint32_t)f2b(v0) | ((uint32_t)f2b(v1) << 16);
            pk.y = (uint32_t)f2b(v2) | ((uint32_t)f2b(v3) << 16);
            const int rowp = px[i] * OUT_ROWS + py[i] + OUT_PAD;
            const int coff = (m - M0) * 32 + (kg << 3);
            const int a = OUT_OFF + (((rowp << OUT_SH) | coff) ^ ((rowp & MSK) << 4));
            *(uint2*)(smem + a) = pk;
        }
    }
}

// ---------------- gather one conv2 half into registers (threads < 512) ----------------
__device__ __forceinline__ void gather_half(const uint8_t* smem,
                                            const float* __restrict__ rooms,
                                            const int* __restrict__ rp,
                                            int gr, int gg, int h, float* yreg)
{
    if ((gg >> 2) != h) return;
    const int gl = gg & 3;
    const int pxr = rp[gr * 2], pyr = rp[gr * 2 + 1];
    const float* rr = rooms + gr * 324;
    float s0=0,s1=0,s2=0,s3=0,s4=0,s5=0,s6=0,s7=0;
#pragma unroll
    for (int ci = 0; ci < 6; ++ci)
#pragma unroll
        for (int cj = 0; cj < 6; ++cj) {
            const float mv = rr[ci * 6 + cj];
            if (mv != 0.f) {
                const int p = (pxr + ci) * 24 + pyr + cj;
                const int a = X3_OFF + (((p << 6) | (gl << 4)) ^ ((p & 3) << 4));
                const v8s v = *(const v8s*)(smem + a);
                s0 = fmaf(b2f((uint16_t)v[0]), mv, s0);
                s1 = fmaf(b2f((uint16_t)v[1]), mv, s1);
                s2 = fmaf(b2f((uint16_t)v[2]), mv, s2);
                s3 = fmaf(b2f((uint16_t)v[3]), mv, s3);
                s4 = fmaf(b2f((uint16_t)v[4]), mv, s4);
                s5 = fmaf(b2f((uint16_t)v[5]), mv, s5);
                s6 = fmaf(b2f((uint16_t)v[6]), mv, s6);
                s7 = fmaf(b2f((uint16_t)v[7]), mv, s7);
            }
        }
    yreg[0]=s0; yreg[1]=s1; yreg[2]=s2; yreg[3]=s3;
    yreg[4]=s4; yreg[5]=s5; yreg[6]=s6; yreg[7]=s7;
}

// ---------------- MLP layer (f32), 1024 threads: 4 outputs each ----------------
template<bool RELU, bool TOGLOBAL>
__device__ __forceinline__ void mlp_layer(uint8_t* smem, int inoff, int outoff,
                                          const float* __restrict__ W,
                                          const float* __restrict__ bias,
                                          float* __restrict__ outg, int tid)
{
    const int og = tid >> 6, r = tid & 63;
    const int ogs = __builtin_amdgcn_readfirstlane(og);
    const int swz = (r & 7) << 4;
    float yrow[64];
#pragma unroll
    for (int cg = 0; cg < 16; ++cg) {
        v4f v = *(const v4f*)(smem + inoff + ((r * 256 + cg * 16) ^ swz));
        yrow[cg*4+0] = v[0]; yrow[cg*4+1] = v[1]; yrow[cg*4+2] = v[2]; yrow[cg*4+3] = v[3];
    }
    float acc[4];
    const float* Wb = W + ogs * 4 * 64;
#pragma unroll
    for (int oo = 0; oo < 4; ++oo) {
        float a = bias[ogs * 4 + oo];
        const float* wr = Wb + oo * 64;
#pragma unroll
        for (int c = 0; c < 64; ++c) a = fmaf(wr[c], yrow[c], a);
        acc[oo] = RELU ? fmaxf(a, 0.f) : a;
    }
    v4f o0 = {acc[0], acc[1], acc[2], acc[3]};
    if (TOGLOBAL) *(v4f*)(outg + r * 64 + ogs * 4) = o0;
    else          *(v4f*)(smem + outoff + ((r * 256 + ogs * 16) ^ swz)) = o0;
}

// ---------------- fused main kernel: one block (16 waves) per sample ----------------
__global__ __launch_bounds__(TPB, 4)
void fused_main(const int* __restrict__ rpos,
                const float* __restrict__ rooms,
                const float* __restrict__ emb,
                const float* __restrict__ b0, const float* __restrict__ b1,
                const float* __restrict__ b2,
                const float* __restrict__ rw0, const float* __restrict__ rb0,
                const float* __restrict__ rw1, const float* __restrict__ rb1,
                const float* __restrict__ rw2, const float* __restrict__ rb2,
                const uint8_t* __restrict__ ws,
                float* __restrict__ out)
{
    __shared__ __align__(16) uint8_t smem[SMEM_BYTES];
    const int tid = threadIdx.x, n = blockIdx.x;
    const int* rp = rpos + n * 128;
    const v8s* wsv = (const v8s*)ws;

    // ---- P1: register scatter -> bf16 X0 (no atomics, no f32 buffer) ----
    if (tid < 768) {
        const int x = (tid * 2731) >> 16;       // tid / 24
        const int y = tid - x * 24;
        float a[26];
#pragma unroll
        for (int c = 0; c < 26; ++c) a[c] = 0.f;
        a[9] = 1.f;                              // background channel
        for (int r = 0; r < 64; ++r) {
            const int ci = x - rp[2 * r], cj = y - rp[2 * r + 1];
            if ((unsigned)ci < 6u && (unsigned)cj < 6u) {
                const int cell = ci * 6 + cj;
                const float* rr = rooms + r * 324;
                const float m = rr[cell];
                if (m != 0.f) {
#pragma unroll
                    for (int c = 0; c < 9; ++c) a[c] += rr[c * 36 + cell];
                    const float* er = emb + r * 16;
#pragma unroll
                    for (int e = 0; e < 16; ++e) a[10 + e] = fmaf(er[e], m, a[10 + e]);
                }
            }
        }
        const int row = x * 28 + y + 2;
        const int swz = (row & 3) << 4;
#pragma unroll
        for (int cg = 0; cg < 4; ++cg) {
            v8s o;
#pragma unroll
            for (int j = 0; j < 8; ++j) {
                const int c = cg * 8 + j;
                o[j] = (short)((c < 26) ? f2b(a[c]) : (uint16_t)0);
            }
            *(v8s*)(smem + X0_OFF + (((row << 6) | (cg << 4)) ^ swz)) = o;
        }
    } else {
        // zero X0 y-pad rows: 128 rows x 4 slots, 256 threads x 2
        const int base = (tid - 768) * 2;
#pragma unroll
        for (int k = 0; k < 2; ++k) {
            const int u = base + k;
            const int rowi = u >> 2, slot = u & 3;
            const int x = rowi >> 2, yp = rowi & 3;
            const int row = x * 28 + ((yp < 2) ? yp : yp + 24);
            *(v8s*)(smem + X0_OFF + (((row << 6) | (slot << 4)) ^ ((row & 3) << 4))) =
                (v8s){0,0,0,0,0,0,0,0};
        }
    }
    __syncthreads();

    // per-thread MFMA geometry
    const int l = tid & 63, wv = tid >> 6, kg = l >> 4;
    int px[3], py[3];
#pragma unroll
    for (int i = 0; i < 3; ++i) {
        const int p = (wv + 16 * i) * 16 + (l & 15);
        const int x = (p * 2731) >> 16;
        px[i] = x; py[i] = p - x * 24;
    }

    // ---- P2: conv0 (26->32, 5x5) + X1 pad zero ----
    {
        if (tid < 256) {
            const int rowi = tid >> 2, slot = tid & 3;
            const int x = rowi >> 1;
            const int rowp = x * 26 + ((rowi & 1) ? 25 : 0);
            *(v8s*)(smem + X1_OFF + (((rowp << 6) | (slot << 4)) ^ ((rowp & 3) << 4))) =
                (v8s){0,0,0,0,0,0,0,0};
        }
        v4f acc[2][3];
#pragma unroll
        for (int m = 0; m < 2; ++m)
#pragma unroll
            for (int i = 0; i < 3; ++i) acc[m][i] = (v4f){0.f,0.f,0.f,0.f};
        conv_core<2,1,25,5,2, X0_OFF,6,28, WS0_U,2>(smem, wsv, l, px, py, acc);
        conv_epi<2,0,2, X1_OFF,6,26,1>(smem, b0, acc, px, py, kg);
    }
    __syncthreads();

    // ---- P3: conv1 (32->64, 3x3) + X2 pad zero ----
    {
        if (tid < 512) {
            const int rowi = tid >> 3, slot = tid & 7;
            const int x = rowi >> 1;
            const int rowp = x * 26 + ((rowi & 1) ? 25 : 0);
            *(v8s*)(smem + X2_OFF + (((rowp << 7) | (slot << 4)) ^ ((rowp & 7) << 4))) =
                (v8s){0,0,0,0,0,0,0,0};
        }
        v4f acc[4][3];
#pragma unroll
        for (int m = 0; m < 4; ++m)
#pragma unroll
            for (int i = 0; i < 3; ++i) acc[m][i] = (v4f){0.f,0.f,0.f,0.f};
        conv_core<4,1,9,3,1, X1_OFF,6,26, WS1_U,4>(smem, wsv, l, px, py, acc);
        conv_epi<4,0,4, X2_OFF,7,26,1>(smem, b1, acc, px, py, kg);
    }
    __syncthreads();

    // ---- P4: conv2 (64->64, 3x3) single K-sweep, two-stage epilogue + gather ----
    float yreg[8];
    {
        v4f acc[4][3];
#pragma unroll
        for (int m = 0; m < 4; ++m)
#pragma unroll
            for (int i = 0; i < 3; ++i) acc[m][i] = (v4f){0.f,0.f,0.f,0.f};
        conv_core<4,2,9,3,1, X2_OFF,7,26, WS2_U,4>(smem, wsv, l, px, py, acc);
        // half 0 (oc 0..31): X3 write does not touch X2, no barrier needed first
        conv_epi<4,0,2, X3_OFF,6,24,0>(smem, b2, acc, px, py, kg);
        __syncthreads();
        if (tid < 512) gather_half(smem, rooms, rp, tid >> 3, tid & 7, 0, yreg);
        __syncthreads();
        // half 1 (oc 32..63)
        conv_epi<4,2,4, X3_OFF,6,24,0>(smem, b2, acc, px, py, kg);
        __syncthreads();
        if (tid < 512) gather_half(smem, rooms, rp, tid >> 3, tid & 7, 1, yreg);
        __syncthreads();
    }

    // ---- P5: assemble Y f32 [r][c] (swizzled rows); thread (gr,gg) holds Y[gr][gg*8..+8]
    if (tid < 512) {
        const int gr = tid >> 3, gg = tid & 7;
        const int base = gr * 256 + gg * 32;
        const int swz = (gr & 7) << 4;
        *(v4f*)(smem + YA_OFF + (base ^ swz))        = (v4f){yreg[0], yreg[1], yreg[2], yreg[3]};
        *(v4f*)(smem + YA_OFF + ((base + 16) ^ swz)) = (v4f){yreg[4], yreg[5], yreg[6], yreg[7]};
    }
    __syncthreads();

    // ---- P6: 3-layer room MLP (f32) ----
    mlp_layer<true,  false>(smem, YA_OFF, YB_OFF, rw0, rb0, nullptr, tid);
    __syncthreads();
    mlp_layer<true,  false>(smem, YB_OFF, YA_OFF, rw1, rb1, nullptr, tid);
    __syncthreads();
    mlp_layer<false, true >(smem, YA_OFF, 0, rw2, rb2, out + n * 4096, tid);
}

extern "C" void kernel_launch(void* const* d_in, const int* in_sizes, int n_in,
                              void* d_out, int out_size, void* d_ws, size_t ws_size,
                              hipStream_t stream) {
    const int*   rpos  = (const int*)  d_in[0];
    const float* rooms = (const float*)d_in[1];
    const float* emb   = (const float*)d_in[2];
    const float* w0    = (const float*)d_in[3];
    const float* b0    = (const float*)d_in[4];
    const float* w1    = (const float*)d_in[5];
    const float* b1    = (const float*)d_in[6];
    const float* w2    = (const float*)d_in[7];
    const float* b2    = (const float*)d_in[8];
    const float* rw0   = (const float*)d_in[9];
    const float* rb0   = (const float*)d_in[10];
    const float* rw1   = (const float*)d_in[11];
    const float* rb1   = (const float*)d_in[12];
    const float* rw2   = (const float*)d_in[13];
    const float* rb2   = (const float*)d_in[14];
    float* out = (float*)d_out;
    uint8_t* ws = (uint8_t*)d_ws;

    const int n = in_sizes[0] / 128;   // samples (512)
    hipLaunchKernelGGL(prep_weights, dim3((WS_UNITS + 255) / 256), dim3(256), 0, stream,
                       w0, w1, w2, ws);
    hipLaunchKernelGGL(fused_main, dim3(n), dim3(TPB), 0, stream,
                       rpos, rooms, emb, b0, b1, b2,
                       rw0, rb0, rw1, rb1, rw2, rb2, ws, out);
}

// Round 5
// 132.585 us; speedup vs baseline: 7.7006x; 1.0010x over previous
//
#include <hip/hip_runtime.h>
#include <stdint.h>

typedef short v8s __attribute__((ext_vector_type(8)));
typedef float v4f __attribute__((ext_vector_type(4)));

#define TPB 1024

// ---- LDS layout (bytes) ----
// scatter : X0 bf16 [32x][28y][32c] rows 64B swz(row&3)<<4   @0        57,344
// conv0   : X0 -> X1 bf16 [32x][26y][32c] rows 64B           @106,496  53,248 (ends 159,744)
// conv1   : X1 -> X2 bf16 [32x][26y][64c] rows 128B swz&7    @0       106,496 (X0 dead)
// conv2   : X2 -> X3 bf16 [768p][32c] rows 64B swz&3         @106,496  49,152 (X1 dead)
// MLP     : Ya f32 @0 (16,384), Yb f32 @16,384 (16,384)               (X2 dead)
#define X0_OFF 0
#define X1_OFF 106496
#define X2_OFF 0
#define X3_OFF 106496
#define YA_OFF 0
#define YB_OFF 16384
#define SMEM_BYTES 159744

// ws fragment bases (16B units): conv0 50 frags, conv1 36, conv2 72 (x64 lanes)
#define WS0_U 0
#define WS1_U 3200
#define WS2_U 5504
#define WS_UNITS 10112

__device__ __forceinline__ uint16_t f2b(float f) {
    uint32_t u = __float_as_uint(f);
    return (uint16_t)((u + 0x7FFFu + ((u >> 16) & 1u)) >> 16);
}
__device__ __forceinline__ float b2f(uint16_t h) {
    return __uint_as_float(((uint32_t)h) << 16);
}

// ---------------- weight prep: pack A-fragments (bf16) into d_ws ----------------
// fid = (t*KF + kf)*MT_TOT + m ; lane l holds W[m*16+(l&15)][kf*32+(l>>4)*8 + j]
__global__ void prep_weights(const float* __restrict__ w0,
                             const float* __restrict__ w1,
                             const float* __restrict__ w2,
                             uint8_t* __restrict__ ws)
{
    int u = blockIdx.x * 256 + threadIdx.x;
    if (u >= WS_UNITS) return;
    int l = u & 63, fid = u >> 6;
    const float* src; int IC, KS_, t, kf, m;
    if (fid < 50)      { src = w0; IC = 26; KS_ = 5; t = fid >> 1; kf = 0; m = fid & 1; }
    else if (fid < 86) { int v = fid - 50; src = w1; IC = 32; KS_ = 3; t = v >> 2; kf = 0; m = v & 3; }
    else               { int v = fid - 86; src = w2; IC = 64; KS_ = 3; t = v >> 3; kf = (v >> 2) & 1; m = v & 3; }
    int oc = m * 16 + (l & 15);
    int kb = kf * 32 + ((l >> 4) * 8);
    int ky = t / KS_, kx = t - ky * KS_;
    v8s out;
#pragma unroll
    for (int j = 0; j < 8; ++j) {
        int k = kb + j;
        float v = (k < IC) ? src[((oc * IC + k) * KS_ + ky) * KS_ + kx] : 0.f;
        out[j] = (short)f2b(v);
    }
    ((v8s*)ws)[u] = out;
}

// ---------------- conv core: tap-decomposed implicit GEMM on MFMA ----------------
template<int MT, int KF, int TAPS, int KS, int PAD,
         int IN_OFF, int IN_SH, int IN_ROWS, int WS_BASE, int MT_TOT>
__device__ __forceinline__ void conv_core(const uint8_t* smem, const v8s* __restrict__ wsv,
                                          int l, const int* px, const int* py,
                                          v4f (&acc)[MT][3])
{
    const int kgoff = ((l >> 4) << 4);
    constexpr int MSK = (IN_SH == 7) ? 7 : 3;
    for (int t = 0; t < TAPS; ++t) {
        const int ky = t / KS, kx = t - ky * KS;
        const int dx = ky - PAD, dy = kx - PAD;
        v8s af[MT][KF];
#pragma unroll
        for (int m = 0; m < MT; ++m)
#pragma unroll
            for (int kf = 0; kf < KF; ++kf)
                af[m][kf] = wsv[WS_BASE + ((t * KF + kf) * MT_TOT + m) * 64 + l];
#pragma unroll
        for (int i = 0; i < 3; ++i) {
            const int xi = px[i] + dx;
            const int rowp = xi * IN_ROWS + py[i] + dy + PAD;   // y via physical pad
            int a = ((rowp << IN_SH) | kgoff) ^ ((rowp & MSK) << 4);
            a = ((unsigned)xi < 32u) ? a : kgoff;               // x OOB -> zeroed row 0
            a += IN_OFF;
            const v8s bf0 = *(const v8s*)(smem + a);
#pragma unroll
            for (int m = 0; m < MT; ++m)
                acc[m][i] = __builtin_amdgcn_mfma_f32_16x16x32_bf16(af[m][0], bf0, acc[m][i], 0, 0, 0);
            if (KF == 2) {
                const v8s bf1 = *(const v8s*)(smem + (a ^ 64));
#pragma unroll
                for (int m = 0; m < MT; ++m)
                    acc[m][i] = __builtin_amdgcn_mfma_f32_16x16x32_bf16(af[m][1], bf1, acc[m][i], 0, 0, 0);
            }
        }
    }
}

// ---------------- conv epilogue: bias+relu+bf16 pack, packed b64 stores ----------------
template<int MTOT, int M0, int M1, int OUT_OFF, int OUT_SH, int OUT_ROWS, int OUT_PAD>
__device__ __forceinline__ void conv_epi(uint8_t* smem, const float* __restrict__ bias,
                                         v4f (&acc)[MTOT][3], const int* px, const int* py, int kg)
{
    constexpr int MSK = (OUT_SH == 7) ? 7 : 3;
#pragma unroll
    for (int m = M0; m < M1; ++m) {
        const float* bp = bias + m * 16 + kg * 4;
        const float bb0 = bp[0], bb1 = bp[1], bb2 = bp[2], bb3 = bp[3];
#pragma unroll
        for (int i = 0; i < 3; ++i) {
            const float v0 = fmaxf(acc[m][i][0] + bb0, 0.f);
            const float v1 = fmaxf(acc[m][i][1] + bb1, 0.f);
            const float v2 = fmaxf(acc[m][i][2] + bb2, 0.f);
            const float v3 = fmaxf(acc[m][i][3] + bb3, 0.f);
            uint2 pk;
            pk.x = (uint32_t)f2b(v0) | ((uint32_t)f2b(v1) << 16);
            pk.y = (uint32_t)f2b(v2) | ((uint32_t)f2b(v3) << 16);
            const int rowp = px[i] * OUT_ROWS + py[i] + OUT_PAD;
            const int coff = (m - M0) * 32 + (kg << 3);
            const int a = OUT_OFF + (((rowp << OUT_SH) | coff) ^ ((rowp & MSK) << 4));
            *(uint2*)(smem + a) = pk;
        }
    }
}

// ---------------- gather one conv2 half into registers (threads < 512) ----------------
__device__ __forceinline__ void gather_half(const uint8_t* smem,
                                            const float* __restrict__ rooms,
                                            const int* __restrict__ rp,
                                            int gr, int gg, int h, float* yreg)
{
    if ((gg >> 2) != h) return;
    const int gl = gg & 3;
    const int pxr = rp[gr * 2], pyr = rp[gr * 2 + 1];
    const float* rr = rooms + gr * 324;
    float s0=0,s1=0,s2=0,s3=0,s4=0,s5=0,s6=0,s7=0;
#pragma unroll
    for (int ci = 0; ci < 6; ++ci)
#pragma unroll
        for (int cj = 0; cj < 6; ++cj) {
            const float mv = rr[ci * 6 + cj];
            if (mv != 0.f) {
                const int p = (pxr + ci) * 24 + pyr + cj;
                const int a = X3_OFF + (((p << 6) | (gl << 4)) ^ ((p & 3) << 4));
                const v8s v = *(const v8s*)(smem + a);
                s0 = fmaf(b2f((uint16_t)v[0]), mv, s0);
                s1 = fmaf(b2f((uint16_t)v[1]), mv, s1);
                s2 = fmaf(b2f((uint16_t)v[2]), mv, s2);
                s3 = fmaf(b2f((uint16_t)v[3]), mv, s3);
                s4 = fmaf(b2f((uint16_t)v[4]), mv, s4);
                s5 = fmaf(b2f((uint16_t)v[5]), mv, s5);
                s6 = fmaf(b2f((uint16_t)v[6]), mv, s6);
                s7 = fmaf(b2f((uint16_t)v[7]), mv, s7);
            }
        }
    yreg[0]=s0; yreg[1]=s1; yreg[2]=s2; yreg[3]=s3;
    yreg[4]=s4; yreg[5]=s5; yreg[6]=s6; yreg[7]=s7;
}

// ---------------- MLP layer (f32), 1024 threads: 4 outputs each ----------------
template<bool RELU, bool TOGLOBAL>
__device__ __forceinline__ void mlp_layer(uint8_t* smem, int inoff, int outoff,
                                          const float* __restrict__ W,
                                          const float* __restrict__ bias,
                                          float* __restrict__ outg, int tid)
{
    const int og = tid >> 6, r = tid & 63;
    const int ogs = __builtin_amdgcn_readfirstlane(og);
    const int swz = (r & 7) << 4;
    float yrow[64];
#pragma unroll
    for (int cg = 0; cg < 16; ++cg) {
        v4f v = *(const v4f*)(smem + inoff + ((r * 256 + cg * 16) ^ swz));
        yrow[cg*4+0] = v[0]; yrow[cg*4+1] = v[1]; yrow[cg*4+2] = v[2]; yrow[cg*4+3] = v[3];
    }
    float acc[4];
    const float* Wb = W + ogs * 4 * 64;
#pragma unroll
    for (int oo = 0; oo < 4; ++oo) {
        float a = bias[ogs * 4 + oo];
        const float* wr = Wb + oo * 64;
#pragma unroll
        for (int c = 0; c < 64; ++c) a = fmaf(wr[c], yrow[c], a);
        acc[oo] = RELU ? fmaxf(a, 0.f) : a;
    }
    v4f o0 = {acc[0], acc[1], acc[2], acc[3]};
    if (TOGLOBAL) *(v4f*)(outg + r * 64 + ogs * 4) = o0;
    else          *(v4f*)(smem + outoff + ((r * 256 + ogs * 16) ^ swz)) = o0;
}

// ---------------- fused main kernel: one block (16 waves) per sample ----------------
// Pin waves/EU to exactly 4 (LDS already caps at 1 block/CU = 4 waves/EU), so the
// backend allocates up to 128 VGPRs instead of spilling to hit an unattainable 8.
__global__ __attribute__((amdgpu_flat_work_group_size(TPB, TPB), amdgpu_waves_per_eu(4, 4)))
void fused_main(const int* __restrict__ rpos,
                const float* __restrict__ rooms,
                const float* __restrict__ emb,
                const float* __restrict__ b0, const float* __restrict__ b1,
                const float* __restrict__ b2,
                const float* __restrict__ rw0, const float* __restrict__ rb0,
                const float* __restrict__ rw1, const float* __restrict__ rb1,
                const float* __restrict__ rw2, const float* __restrict__ rb2,
                const uint8_t* __restrict__ ws,
                float* __restrict__ out)
{
    __shared__ __align__(16) uint8_t smem[SMEM_BYTES];
    const int tid = threadIdx.x, n = blockIdx.x;
    const int* rp = rpos + n * 128;
    const v8s* wsv = (const v8s*)ws;

    // ---- P1: register scatter -> bf16 X0 (no atomics, no f32 buffer) ----
    if (tid < 768) {
        const int x = (tid * 2731) >> 16;       // tid / 24
        const int y = tid - x * 24;
        float a[26];
#pragma unroll
        for (int c = 0; c < 26; ++c) a[c] = 0.f;
        a[9] = 1.f;                              // background channel
        for (int r = 0; r < 64; ++r) {
            const int ci = x - rp[2 * r], cj = y - rp[2 * r + 1];
            if ((unsigned)ci < 6u && (unsigned)cj < 6u) {
                const int cell = ci * 6 + cj;
                const float* rr = rooms + r * 324;
                const float m = rr[cell];
                if (m != 0.f) {
#pragma unroll
                    for (int c = 0; c < 9; ++c) a[c] += rr[c * 36 + cell];
                    const float* er = emb + r * 16;
#pragma unroll
                    for (int e = 0; e < 16; ++e) a[10 + e] = fmaf(er[e], m, a[10 + e]);
                }
            }
        }
        const int row = x * 28 + y + 2;
        const int swz = (row & 3) << 4;
#pragma unroll
        for (int cg = 0; cg < 4; ++cg) {
            v8s o;
#pragma unroll
            for (int j = 0; j < 8; ++j) {
                const int c = cg * 8 + j;
                o[j] = (short)((c < 26) ? f2b(a[c]) : (uint16_t)0);
            }
            *(v8s*)(smem + X0_OFF + (((row << 6) | (cg << 4)) ^ swz)) = o;
        }
    } else {
        // zero X0 y-pad rows: 128 rows x 4 slots, 256 threads x 2
        const int base = (tid - 768) * 2;
#pragma unroll
        for (int k = 0; k < 2; ++k) {
            const int u = base + k;
            const int rowi = u >> 2, slot = u & 3;
            const int x = rowi >> 2, yp = rowi & 3;
            const int row = x * 28 + ((yp < 2) ? yp : yp + 24);
            *(v8s*)(smem + X0_OFF + (((row << 6) | (slot << 4)) ^ ((row & 3) << 4))) =
                (v8s){0,0,0,0,0,0,0,0};
        }
    }
    __syncthreads();

    // per-thread MFMA geometry
    const int l = tid & 63, wv = tid >> 6, kg = l >> 4;
    int px[3], py[3];
#pragma unroll
    for (int i = 0; i < 3; ++i) {
        const int p = (wv + 16 * i) * 16 + (l & 15);
        const int x = (p * 2731) >> 16;
        px[i] = x; py[i] = p - x * 24;
    }

    // ---- P2: conv0 (26->32, 5x5) + X1 pad zero ----
    {
        if (tid < 256) {
            const int rowi = tid >> 2, slot = tid & 3;
            const int x = rowi >> 1;
            const int rowp = x * 26 + ((rowi & 1) ? 25 : 0);
            *(v8s*)(smem + X1_OFF + (((rowp << 6) | (slot << 4)) ^ ((rowp & 3) << 4))) =
                (v8s){0,0,0,0,0,0,0,0};
        }
        v4f acc[2][3];
#pragma unroll
        for (int m = 0; m < 2; ++m)
#pragma unroll
            for (int i = 0; i < 3; ++i) acc[m][i] = (v4f){0.f,0.f,0.f,0.f};
        conv_core<2,1,25,5,2, X0_OFF,6,28, WS0_U,2>(smem, wsv, l, px, py, acc);
        conv_epi<2,0,2, X1_OFF,6,26,1>(smem, b0, acc, px, py, kg);
    }
    __syncthreads();

    // ---- P3: conv1 (32->64, 3x3) + X2 pad zero ----
    {
        if (tid < 512) {
            const int rowi = tid >> 3, slot = tid & 7;
            const int x = rowi >> 1;
            const int rowp = x * 26 + ((rowi & 1) ? 25 : 0);
            *(v8s*)(smem + X2_OFF + (((rowp << 7) | (slot << 4)) ^ ((rowp & 7) << 4))) =
                (v8s){0,0,0,0,0,0,0,0};
        }
        v4f acc[4][3];
#pragma unroll
        for (int m = 0; m < 4; ++m)
#pragma unroll
            for (int i = 0; i < 3; ++i) acc[m][i] = (v4f){0.f,0.f,0.f,0.f};
        conv_core<4,1,9,3,1, X1_OFF,6,26, WS1_U,4>(smem, wsv, l, px, py, acc);
        conv_epi<4,0,4, X2_OFF,7,26,1>(smem, b1, acc, px, py, kg);
    }
    __syncthreads();

    // ---- P4: conv2 (64->64, 3x3) single K-sweep, two-stage epilogue + gather ----
    float yreg[8];
    {
        v4f acc[4][3];
#pragma unroll
        for (int m = 0; m < 4; ++m)
#pragma unroll
            for (int i = 0; i < 3; ++i) acc[m][i] = (v4f){0.f,0.f,0.f,0.f};
        conv_core<4,2,9,3,1, X2_OFF,7,26, WS2_U,4>(smem, wsv, l, px, py, acc);
        // half 0 (oc 0..31): X3 write does not touch X2, no barrier needed first
        conv_epi<4,0,2, X3_OFF,6,24,0>(smem, b2, acc, px, py, kg);
        __syncthreads();
        if (tid < 512) gather_half(smem, rooms, rp, tid >> 3, tid & 7, 0, yreg);
        __syncthreads();
        // half 1 (oc 32..63)
        conv_epi<4,2,4, X3_OFF,6,24,0>(smem, b2, acc, px, py, kg);
        __syncthreads();
        if (tid < 512) gather_half(smem, rooms, rp, tid >> 3, tid & 7, 1, yreg);
        __syncthreads();
    }

    // ---- P5: assemble Y f32 [r][c] (swizzled rows); thread (gr,gg) holds Y[gr][gg*8..+8]
    if (tid < 512) {
        const int gr = tid >> 3, gg = tid & 7;
        const int base = gr * 256 + gg * 32;
        const int swz = (gr & 7) << 4;
        *(v4f*)(smem + YA_OFF + (base ^ swz))        = (v4f){yreg[0], yreg[1], yreg[2], yreg[3]};
        *(v4f*)(smem + YA_OFF + ((base + 16) ^ swz)) = (v4f){yreg[4], yreg[5], yreg[6], yreg[7]};
    }
    __syncthreads();

    // ---- P6: 3-layer room MLP (f32) ----
    mlp_layer<true,  false>(smem, YA_OFF, YB_OFF, rw0, rb0, nullptr, tid);
    __syncthreads();
    mlp_layer<true,  false>(smem, YB_OFF, YA_OFF, rw1, rb1, nullptr, tid);
    __syncthreads();
    mlp_layer<false, true >(smem, YA_OFF, 0, rw2, rb2, out + n * 4096, tid);
}

extern "C" void kernel_launch(void* const* d_in, const int* in_sizes, int n_in,
                              void* d_out, int out_size, void* d_ws, size_t ws_size,
                              hipStream_t stream) {
    const int*   rpos  = (const int*)  d_in[0];
    const float* rooms = (const float*)d_in[1];
    const float* emb   = (const float*)d_in[2];
    const float* w0    = (const float*)d_in[3];
    const float* b0    = (const float*)d_in[4];
    const float* w1    = (const float*)d_in[5];
    const float* b1    = (const float*)d_in[6];
    const float* w2    = (const float*)d_in[7];
    const float* b2    = (const float*)d_in[8];
    const float* rw0   = (const float*)d_in[9];
    const float* rb0   = (const float*)d_in[10];
    const float* rw1   = (const float*)d_in[11];
    const float* rb1   = (const float*)d_in[12];
    const float* rw2   = (const float*)d_in[13];
    const float* rb2   = (const float*)d_in[14];
    float* out = (float*)d_out;
    uint8_t* ws = (uint8_t*)d_ws;

    const int n = in_sizes[0] / 128;   // samples (512)
    hipLaunchKernelGGL(prep_weights, dim3((WS_UNITS + 255) / 256), dim3(256), 0, stream,
                       w0, w1, w2, ws);
    hipLaunchKernelGGL(fused_main, dim3(n), dim3(TPB), 0, stream,
                       rpos, rooms, emb, b0, b1, b2,
                       rw0, rb0, rw1, rb1, rw2, rb2, ws, out);
}